// Round 9
// baseline (458.066 us; speedup 1.0000x reference)
//
#include <hip/hip_runtime.h>
#include <cstdint>
#include <cstddef>

// Dtypes PROVEN fp32 (R2 bf16-read -> NaN; R4 fp32-read -> pass, absmax 0.0078).
#define N_NODES 8192
#define FIN 256
#define FOUT 128
#define MT 64                 // rows per block in gat kernel
#define KC 256                // j-chunk size
#define JS 8                  // j slices (partial softmax, merged in fin_kernel)
#define JW (N_NODES / JS)     // 1024 columns per slice
#define NCHS (JW / KC)        // 4 chunks per block
#define LOG2E 1.4426950408889634f

typedef __attribute__((ext_vector_type(8))) short bf16x8;
typedef __attribute__((ext_vector_type(4))) float f32x4;
typedef __attribute__((ext_vector_type(2))) unsigned int u32x2;

__device__ __forceinline__ float bf2f(unsigned short u) {
    union { unsigned int i; float f; } v; v.i = ((unsigned int)u) << 16; return v.f;
}
__device__ __forceinline__ unsigned short f2bf(float f) {
    union { float f; unsigned int i; } v; v.f = f;
    unsigned int r = (v.i + 0x7FFFu + ((v.i >> 16) & 1u)) >> 16;
    return (unsigned short)r;
}
__device__ __forceinline__ unsigned int pack_bf16(float a, float b) {
    return (unsigned)f2bf(a) | ((unsigned)f2bf(b) << 16);
}

// whB fragment-order layout: tile (kb, fb) holds Wh[j=kb*32+quad*8+e][f=fb*16+sl]
// at element ((kb*8+fb)*512 + (quad*16+sl)*8 + e) -> a wave's B-load is one
// contiguous 1 KB burst.
__device__ __forceinline__ size_t whb_idx(int j, int f) {
    return ((size_t)((j >> 5) * 8 + (f >> 4)) << 9) + (((j >> 3) & 3) << 7)
         + ((f & 15) << 3) + (j & 7);
}

// ---------------- Kernel P: pack adj (int32 0/1) -> bitmask ------------------
// Row r, word w (u64) covers cols [w*64, w*64+64), bit b <-> col w*64+b.
__global__ __launch_bounds__(256) void pack_kernel(const int* __restrict__ adj,
                                                   unsigned long long* __restrict__ bits) {
    const int t = threadIdx.x;
    const int lane = t & 63;
    const int wv = t >> 6;
    const int wid = blockIdx.x * 4 + wv;            // 0..4095
#pragma unroll
    for (int pass = 0; pass < 2; ++pass) {
        const int row = wid + pass * 4096;
        const int* ar = adj + (size_t)row * N_NODES;
        unsigned long long k0 = 0, k1 = 0;
#pragma unroll
        for (int seg = 0; seg < 64; ++seg) {        // cols [0, 4096)
            unsigned long long m = __ballot(ar[seg * 64 + lane] > 0);
            if (lane == seg) k0 = m;
        }
#pragma unroll
        for (int seg = 0; seg < 64; ++seg) {        // cols [4096, 8192)
            unsigned long long m = __ballot(ar[4096 + seg * 64 + lane] > 0);
            if (lane == seg) k1 = m;
        }
        unsigned long long* br = bits + (size_t)row * 128;
        br[lane] = k0;                               // coalesced 512 B/wave
        br[64 + lane] = k1;
    }
}

// ---------------- Kernel A: whB = fragment-ordered bf16 (h @ W^T) -------------
__global__ __launch_bounds__(256) void wh_kernel(const float* __restrict__ h,
                                                 const float* __restrict__ W,
                                                 unsigned short* __restrict__ whB) {
    __shared__ float hT[64][FIN + 5];   // stride 261 (odd)
    const int t = threadIdx.x;
    const int i0 = blockIdx.x * 64;
    const int f0 = blockIdx.y * 32;
#pragma unroll
    for (int c = 0; c < 16; ++c) {       // 64x256 floats, float4-coalesced
        int chunk = c * 256 + t;
        int row = chunk >> 6, col = (chunk & 63) * 4;
        f32x4 v = *(const f32x4*)&h[(size_t)(i0 + row) * FIN + col];
        hT[row][col] = v[0]; hT[row][col + 1] = v[1];
        hT[row][col + 2] = v[2]; hT[row][col + 3] = v[3];
    }
    __syncthreads();
    const int lane = t & 63;
    const int fb8 = __builtin_amdgcn_readfirstlane(f0 + (t >> 6) * 8); // wave -> 8 f
    const float* w0 = W + (size_t)fb8 * FIN;
    float acc[8] = {0.f, 0.f, 0.f, 0.f, 0.f, 0.f, 0.f, 0.f};
    for (int k = 0; k < FIN; k += 4) {
        float h0 = hT[lane][k],     h1 = hT[lane][k + 1];
        float h2 = hT[lane][k + 2], h3 = hT[lane][k + 3];
#pragma unroll
        for (int c = 0; c < 8; ++c) {
            const float* wr = w0 + c * FIN;   // uniform -> s_load
            acc[c] += h0 * wr[k] + h1 * wr[k + 1] + h2 * wr[k + 2] + h3 * wr[k + 3];
        }
    }
    const int i = i0 + lane;
#pragma unroll
    for (int c = 0; c < 8; ++c)
        whB[whb_idx(i, fb8 + c)] = f2bf(acc[c]);
}

// ---------------- Kernel B: s1'[i], s2'[i] = (Wh@a)*log2e --------------------
__global__ __launch_bounds__(256) void s_kernel(const unsigned short* __restrict__ whB,
                                                const float* __restrict__ a1,
                                                const float* __restrict__ a2,
                                                float* __restrict__ s1,
                                                float* __restrict__ s2) {
    __shared__ float p1[4][64], p2[4][64];
    const int t = threadIdx.x;
    const int l = t & 63;
    const int g = t >> 6;
    const int i = blockIdx.x * 64 + l;
    float acc1 = 0.f, acc2 = 0.f;
#pragma unroll
    for (int fb = g * 2; fb < g * 2 + 2; ++fb) {
#pragma unroll
        for (int sl = 0; sl < 16; ++sl) {
            int f = fb * 16 + sl;
            float v = bf2f(whB[whb_idx(i, f)]);
            acc1 += v * a1[f];
            acc2 += v * a2[f];
        }
    }
    p1[g][l] = acc1; p2[g][l] = acc2;
    __syncthreads();
    if (g == 0) {
        s1[i] = (p1[0][l] + p1[1][l] + p1[2][l] + p1[3][l]) * LOG2E;
        s2[i] = (p2[0][l] + p2[1][l] + p2[2][l] + p2[3][l]) * LOG2E;
    }
}

// ---------------- Kernel C: fused mask+softmax-partial+PV MFMA ----------------
// grid 1024 (= 128 i-blocks x 8 j-slices), 4 blocks/CU. 64 rows/block.
// B-fragment traffic = (N/MT)*2MB = 256 MB total (halved vs MT=32).
__global__ __launch_bounds__(256, 4) void gat_kernel(const unsigned long long* __restrict__ bits,
                                                     const unsigned short* __restrict__ whB,
                                                     const float* __restrict__ s1,
                                                     const float* __restrict__ s2,
                                                     float* __restrict__ out,     // slice-0 num
                                                     float* __restrict__ nums,    // slices 1..7
                                                     float* __restrict__ dens) {  // 8 x N
    __shared__ __align__(16) unsigned short sP[MT][KC + 8];
    __shared__ float sDen[MT];
    __shared__ float sS1[MT];
    const int t = threadIdx.x;
    const int slice = blockIdx.x & (JS - 1);
    const int i0 = (blockIdx.x >> 3) * MT;
    const int jb = slice * JW;
    const int kb0 = slice * (JW / 32);
    float* __restrict__ num = slice ? (nums + (size_t)(slice - 1) * N_NODES * FOUT) : out;
    float* __restrict__ den = dens + (size_t)slice * N_NODES;
    if (t < MT) { sDen[t] = 0.f; sS1[t] = s1[i0 + t]; }
    __syncthreads();

    const int r0 = t >> 4;       // 0..15: P rows r0 + 16*m, m=0..3
    const int s  = t & 15;       // 16 consecutive cols [s*16, s*16+16)
    const int lane = t & 63;
    const int quad = lane >> 4;
    const int sl = lane & 15;
    const int wv = t >> 6;       // wave -> 32 features (fb pair wv*2, wv*2+1)
    const unsigned long long* bR[4];
    float s1r[4];
#pragma unroll
    for (int m = 0; m < 4; ++m) {
        bR[m] = bits + (size_t)(i0 + r0 + 16 * m) * 128;
        s1r[m] = sS1[r0 + 16 * m];
    }
    const int shft = (s & 3) * 16;

    f32x4 acc[4][2];
#pragma unroll
    for (int m = 0; m < 4; ++m) {
        acc[m][0] = (f32x4){0.f, 0.f, 0.f, 0.f};
        acc[m][1] = (f32x4){0.f, 0.f, 0.f, 0.f};
    }

    // prefetch chunk 0: mask words (one per row-group) + s2 for 16 cols
    int wi = (jb >> 6) + (s >> 2);
    unsigned long long bw[4];
#pragma unroll
    for (int m = 0; m < 4; ++m) bw[m] = bR[m][wi];
    f32x4 sv[4];
#pragma unroll
    for (int q = 0; q < 4; ++q) sv[q] = *(const f32x4*)&s2[jb + s * 16 + q * 4];

    for (int ch = 0; ch < NCHS; ++ch) {
        unsigned int mm[4];
#pragma unroll
        for (int m = 0; m < 4; ++m) mm[m] = (unsigned int)(bw[m] >> shft) & 0xFFFFu;
        // ---- build P tile (bf16, exp2 domain) + row-sum partials ----
        float part[4] = {0.f, 0.f, 0.f, 0.f};
#pragma unroll
        for (int q = 0; q < 4; ++q) {
#pragma unroll
            for (int m = 0; m < 4; ++m) {
                float p[4];
#pragma unroll
                for (int r = 0; r < 4; ++r) {
                    float y = s1r[m] + sv[q][r];
                    y = fmaxf(y, 0.2f * y);                 // leaky (exp2 domain)
                    float e = __builtin_amdgcn_exp2f(y);
                    p[r] = ((mm[m] >> (q * 4 + r)) & 1u) ? e : 0.f;
                    part[m] += p[r];
                }
                u32x2 pk;
                pk.x = pack_bf16(p[0], p[1]);
                pk.y = pack_bf16(p[2], p[3]);
                *(u32x2*)&sP[r0 + 16 * m][s * 16 + q * 4] = pk;
            }
        }
        // ---- prefetch next chunk's bits/s2 ----
        if (ch + 1 < NCHS) {
            int jn = jb + (ch + 1) * KC;
            int wni = (jn >> 6) + (s >> 2);
#pragma unroll
            for (int m = 0; m < 4; ++m) bw[m] = bR[m][wni];
#pragma unroll
            for (int q = 0; q < 4; ++q) sv[q] = *(const f32x4*)&s2[jn + s * 16 + q * 4];
        }
        // ---- reduce partials across the 16 lanes sharing a row-group ----
#pragma unroll
        for (int m = 0; m < 4; ++m) {
            part[m] += __shfl_xor(part[m], 1);
            part[m] += __shfl_xor(part[m], 2);
            part[m] += __shfl_xor(part[m], 4);
            part[m] += __shfl_xor(part[m], 8);
        }
        if (s == 0) {
#pragma unroll
            for (int m = 0; m < 4; ++m) sDen[r0 + 16 * m] += part[m];
        }
        __syncthreads();
        // ---- MFMA: NUM[64 x 128] += P[64 x 256] @ Wh[256 x 128] ----
#pragma unroll
        for (int kq = 0; kq < KC / 32; ++kq) {
            int kb = kb0 + ch * (KC / 32) + kq;
            const unsigned short* bp = whB + ((size_t)(kb * 8 + wv * 2) << 9) + lane * 8;
            bf16x8 b0 = *(const bf16x8*)bp;          // contiguous 1 KB per wave
            bf16x8 b1 = *(const bf16x8*)(bp + 512);
#pragma unroll
            for (int m = 0; m < 4; ++m) {
                bf16x8 am = *(const bf16x8*)&sP[m * 16 + sl][kq * 32 + quad * 8];
                acc[m][0] = __builtin_amdgcn_mfma_f32_16x16x32_bf16(am, b0, acc[m][0], 0, 0, 0);
                acc[m][1] = __builtin_amdgcn_mfma_f32_16x16x32_bf16(am, b1, acc[m][1], 0, 0, 0);
            }
        }
        __syncthreads();
    }
    // ---- epilogue: raw partials (divide + ELU in fin_kernel) ----
    if (t < MT) den[i0 + t] = sDen[t];
#pragma unroll
    for (int m = 0; m < 4; ++m) {
#pragma unroll
        for (int nn = 0; nn < 2; ++nn) {
#pragma unroll
            for (int r = 0; r < 4; ++r) {
                int row = m * 16 + quad * 4 + r;     // D row=(lane>>4)*4+reg, col=lane&15
                num[(size_t)(i0 + row) * FOUT + wv * 32 + nn * 16 + sl] = acc[m][nn][r];
            }
        }
    }
}

// ---------------- Kernel D: merge 8 slices, divide, ELU (in-place) -----------
__global__ __launch_bounds__(256) void fin_kernel(float* __restrict__ out,      // = num0
                                                  const float* __restrict__ nums,
                                                  const float* __restrict__ dens) {
    const int idx = blockIdx.x * 256 + threadIdx.x;
    const int i = idx >> 7;                         // FOUT = 128
    const size_t NF = (size_t)N_NODES * FOUT;
    float numv = out[idx];
#pragma unroll
    for (int k = 0; k < JS - 1; ++k) numv += nums[k * NF + idx];
    float denv = 0.f;
#pragma unroll
    for (int k = 0; k < JS; ++k) denv += dens[k * N_NODES + i];
    float v = numv / fmaxf(denv, 1e-30f);
    out[idx] = (v > 0.f) ? v : expm1f(v);
}

extern "C" void kernel_launch(void* const* d_in, const int* in_sizes, int n_in,
                              void* d_out, int out_size, void* d_ws, size_t ws_size,
                              hipStream_t stream) {
    const float* h   = (const float*)d_in[0];
    const int*   adj = (const int*)d_in[1];
    const float* W   = (const float*)d_in[2];
    const float* a1  = (const float*)d_in[3];
    const float* a2  = (const float*)d_in[4];

    // d_ws layout (~41 MB used):
    //   [0, 2MB)    whB (bf16, fragment-ordered)
    //   [2, 10MB)   bitmask (8192 rows x 128 u64)
    //   [10MB..)    s1 | s2 | dens(8xN) | nums(7 x N*FOUT)
    char* ws = (char*)d_ws;
    unsigned short*     whB  = (unsigned short*)ws;
    unsigned long long* bits = (unsigned long long*)(ws + (2u << 20));
    float* s1   = (float*)(ws + (10u << 20));
    float* s2   = s1 + N_NODES;
    float* dens = s2 + N_NODES;
    float* nums = dens + JS * N_NODES;
    float* out  = (float*)d_out;

    pack_kernel<<<dim3(1024), 256, 0, stream>>>(adj, bits);
    wh_kernel<<<dim3(N_NODES / 64, FOUT / 32), 256, 0, stream>>>(h, W, whB);
    s_kernel<<<dim3(N_NODES / 64), 256, 0, stream>>>(whB, a1, a2, s1, s2);
    gat_kernel<<<dim3((N_NODES / MT) * JS), 256, 0, stream>>>(bits, whB, s1, s2,
                                                              out, nums, dens);
    fin_kernel<<<dim3(N_NODES * FOUT / 256), 256, 0, stream>>>(out, nums, dens);
}

// Round 10
// 446.110 us; speedup vs baseline: 1.0268x; 1.0268x over previous
//
#include <hip/hip_runtime.h>
#include <cstdint>
#include <cstddef>

// Dtypes PROVEN fp32 (R2 bf16-read -> NaN; R4 fp32-read -> pass, absmax 0.0078).
#define N_NODES 8192
#define FIN 256
#define FOUT 128
#define JS 8                  // j slices (partial softmax, merged in fin_kernel)
#define JW (N_NODES / JS)     // 1024 columns per slice
#define KCH (JW / 32)         // 32 k-chunks of 32 cols per wave
#define LOG2E 1.4426950408889634f

typedef __attribute__((ext_vector_type(8))) short bf16x8;
typedef __attribute__((ext_vector_type(4))) float f32x4;
typedef __attribute__((ext_vector_type(4))) int i32x4;

__device__ __forceinline__ float bf2f(unsigned short u) {
    union { unsigned int i; float f; } v; v.i = ((unsigned int)u) << 16; return v.f;
}
__device__ __forceinline__ unsigned short f2bf(float f) {
    union { float f; unsigned int i; } v; v.f = f;
    unsigned int r = (v.i + 0x7FFFu + ((v.i >> 16) & 1u)) >> 16;
    return (unsigned short)r;
}
__device__ __forceinline__ unsigned int pack_bf16(float a, float b) {
    return (unsigned)f2bf(a) | ((unsigned)f2bf(b) << 16);
}

// whB fragment-order layout: tile (kb, fb) holds Wh[j=kb*32+quad*8+e][f=fb*16+sl]
// at element ((kb*8+fb)*512 + (quad*16+sl)*8 + e) -> a wave's B-load is one
// contiguous 1 KB burst.
__device__ __forceinline__ size_t whb_idx(int j, int f) {
    return ((size_t)((j >> 5) * 8 + (f >> 4)) << 9) + (((j >> 3) & 3) << 7)
         + ((f & 15) << 3) + (j & 7);
}

// ---------------- Kernel A: whB = fragment-ordered bf16 (h @ W^T) -------------
__global__ __launch_bounds__(256) void wh_kernel(const float* __restrict__ h,
                                                 const float* __restrict__ W,
                                                 unsigned short* __restrict__ whB) {
    __shared__ float hT[64][FIN + 5];   // stride 261 (odd)
    const int t = threadIdx.x;
    const int i0 = blockIdx.x * 64;
    const int f0 = blockIdx.y * 32;
#pragma unroll
    for (int c = 0; c < 16; ++c) {       // 64x256 floats, float4-coalesced
        int chunk = c * 256 + t;
        int row = chunk >> 6, col = (chunk & 63) * 4;
        f32x4 v = *(const f32x4*)&h[(size_t)(i0 + row) * FIN + col];
        hT[row][col] = v[0]; hT[row][col + 1] = v[1];
        hT[row][col + 2] = v[2]; hT[row][col + 3] = v[3];
    }
    __syncthreads();
    const int lane = t & 63;
    const int fb8 = __builtin_amdgcn_readfirstlane(f0 + (t >> 6) * 8); // wave -> 8 f
    const float* w0 = W + (size_t)fb8 * FIN;
    float acc[8] = {0.f, 0.f, 0.f, 0.f, 0.f, 0.f, 0.f, 0.f};
    for (int k = 0; k < FIN; k += 4) {
        float h0 = hT[lane][k],     h1 = hT[lane][k + 1];
        float h2 = hT[lane][k + 2], h3 = hT[lane][k + 3];
#pragma unroll
        for (int c = 0; c < 8; ++c) {
            const float* wr = w0 + c * FIN;   // uniform -> s_load
            acc[c] += h0 * wr[k] + h1 * wr[k + 1] + h2 * wr[k + 2] + h3 * wr[k + 3];
        }
    }
    const int i = i0 + lane;
#pragma unroll
    for (int c = 0; c < 8; ++c)
        whB[whb_idx(i, fb8 + c)] = f2bf(acc[c]);
}

// ---------------- Kernel B: s1'[i], s2'[i] = (Wh@a)*log2e --------------------
__global__ __launch_bounds__(256) void s_kernel(const unsigned short* __restrict__ whB,
                                                const float* __restrict__ a1,
                                                const float* __restrict__ a2,
                                                float* __restrict__ s1,
                                                float* __restrict__ s2) {
    __shared__ float p1[4][64], p2[4][64];
    const int t = threadIdx.x;
    const int l = t & 63;
    const int g = t >> 6;
    const int i = blockIdx.x * 64 + l;
    float acc1 = 0.f, acc2 = 0.f;
#pragma unroll
    for (int fb = g * 2; fb < g * 2 + 2; ++fb) {
#pragma unroll
        for (int sl = 0; sl < 16; ++sl) {
            int f = fb * 16 + sl;
            float v = bf2f(whB[whb_idx(i, f)]);
            acc1 += v * a1[f];
            acc2 += v * a2[f];
        }
    }
    p1[g][l] = acc1; p2[g][l] = acc2;
    __syncthreads();
    if (g == 0) {
        s1[i] = (p1[0][l] + p1[1][l] + p1[2][l] + p1[3][l]) * LOG2E;
        s2[i] = (p2[0][l] + p2[1][l] + p2[2][l] + p2[3][l]) * LOG2E;
    }
}

// ---------------- Kernel C: BARRIER-FREE fused mask+softmax+PV MFMA ----------
// Each wave owns 32 rows x JW cols: builds P in A-fragment registers directly
// (no LDS, no __syncthreads). Grid 512 blocks x 4 waves = 2048 waves, all
// co-resident (8 waves/CU). adj streamed once, in-loop, per-lane.
__global__ __launch_bounds__(256) void gat_kernel(const int* __restrict__ adj,
                                                  const unsigned short* __restrict__ whB,
                                                  const float* __restrict__ s1,
                                                  const float* __restrict__ s2,
                                                  float* __restrict__ out,     // slice-0 num
                                                  float* __restrict__ nums,    // slices 1..7
                                                  float* __restrict__ dens) {  // 8 x N
    const int t = threadIdx.x;
    const int w = t >> 6;
    const int lane = t & 63;
    const int sl = lane & 15;
    const int quad = lane >> 4;
    const int slice = blockIdx.x & (JS - 1);
    const int rg = (blockIdx.x >> 3) * 4 + w;        // 0..255 row-group
    const int row0 = rg * 32;
    const int jb = slice * JW;
    float* __restrict__ num = slice ? (nums + (size_t)(slice - 1) * N_NODES * FOUT) : out;
    float* __restrict__ den = dens + (size_t)slice * N_NODES;

    const float s1a = s1[row0 + sl];                 // row of m-tile 0
    const float s1b = s1[row0 + 16 + sl];            // row of m-tile 1
    const int* aR0 = adj + (size_t)(row0 + sl) * N_NODES + jb + quad * 8;
    const int* aR1 = aR0 + (size_t)16 * N_NODES;
    const float* s2p = s2 + jb + quad * 8;

    f32x4 acc[2][8];
#pragma unroll
    for (int m = 0; m < 2; ++m)
#pragma unroll
        for (int fb = 0; fb < 8; ++fb) acc[m][fb] = (f32x4){0.f, 0.f, 0.f, 0.f};

    float d0 = 0.f, d1 = 0.f;

    // register prefetch, depth 1 (no barriers -> loads fly across iterations)
    i32x4 pa0 = *(const i32x4*)(aR0);
    i32x4 pa1 = *(const i32x4*)(aR0 + 4);
    i32x4 pb0 = *(const i32x4*)(aR1);
    i32x4 pb1 = *(const i32x4*)(aR1 + 4);
    f32x4 ps0 = *(const f32x4*)(s2p);
    f32x4 ps1 = *(const f32x4*)(s2p + 4);

#pragma unroll 1
    for (int ch = 0; ch < KCH; ++ch) {
        i32x4 ca0 = pa0, ca1 = pa1, cb0 = pb0, cb1 = pb1;
        f32x4 cs0 = ps0, cs1 = ps1;
        if (ch + 1 < KCH) {
            int o = (ch + 1) * 32;
            pa0 = *(const i32x4*)(aR0 + o);
            pa1 = *(const i32x4*)(aR0 + o + 4);
            pb0 = *(const i32x4*)(aR1 + o);
            pb1 = *(const i32x4*)(aR1 + o + 4);
            ps0 = *(const f32x4*)(s2p + o);
            ps1 = *(const f32x4*)(s2p + o + 4);
        }
        // ---- B-fragments: 8 contiguous 1 KB wave-bursts (issue early) ----
        const int kb = jb / 32 + ch;
        const unsigned short* bp = whB + ((size_t)(kb * 8) << 9) + lane * 8;
        bf16x8 B[8];
#pragma unroll
        for (int fb = 0; fb < 8; ++fb) B[fb] = *(const bf16x8*)(bp + ((size_t)fb << 9));
        // ---- P in A-frag layout: lane holds P[sl][quad*8+e], e=0..7 ----
        float p0[8], p1[8];
#pragma unroll
        for (int e = 0; e < 8; ++e) {
            float sc = (e < 4) ? cs0[e] : cs1[e - 4];
            int m0 = (e < 4) ? ca0[e] : ca1[e - 4];
            int m1 = (e < 4) ? cb0[e] : cb1[e - 4];
            float y0 = s1a + sc;
            float y1 = s1b + sc;
            y0 = fmaxf(y0, 0.2f * y0);               // leaky (exp2 domain)
            y1 = fmaxf(y1, 0.2f * y1);
            float e0 = __builtin_amdgcn_exp2f(y0);
            float e1 = __builtin_amdgcn_exp2f(y1);
            p0[e] = (m0 > 0) ? e0 : 0.f;
            p1[e] = (m1 > 0) ? e1 : 0.f;
            d0 += p0[e];
            d1 += p1[e];
        }
        union { bf16x8 v; unsigned int u[4]; } A0, A1;
#pragma unroll
        for (int q = 0; q < 4; ++q) {
            A0.u[q] = pack_bf16(p0[2 * q], p0[2 * q + 1]);
            A1.u[q] = pack_bf16(p1[2 * q], p1[2 * q + 1]);
        }
        // ---- 16 MFMA: NUM[32x128] += P[32x32] @ Wh[32x128] ----
#pragma unroll
        for (int fb = 0; fb < 8; ++fb) {
            acc[0][fb] = __builtin_amdgcn_mfma_f32_16x16x32_bf16(A0.v, B[fb], acc[0][fb], 0, 0, 0);
            acc[1][fb] = __builtin_amdgcn_mfma_f32_16x16x32_bf16(A1.v, B[fb], acc[1][fb], 0, 0, 0);
        }
    }
    // ---- denominator: reduce across quads (lanes sl, sl+16, sl+32, sl+48) ----
    d0 += __shfl_xor(d0, 16); d0 += __shfl_xor(d0, 32);
    d1 += __shfl_xor(d1, 16); d1 += __shfl_xor(d1, 32);
    if (lane < 16) {
        den[row0 + lane] = d0;
        den[row0 + 16 + lane] = d1;
    }
    // ---- epilogue: raw partials (divide + ELU in fin_kernel) ----
#pragma unroll
    for (int m = 0; m < 2; ++m)
#pragma unroll
        for (int fb = 0; fb < 8; ++fb)
#pragma unroll
            for (int r = 0; r < 4; ++r) {
                int row = row0 + m * 16 + quad * 4 + r;   // D: row=quad*4+r, col=sl
                num[(size_t)row * FOUT + fb * 16 + sl] = acc[m][fb][r];
            }
}

// ---------------- Kernel D: merge 8 slices, divide, ELU (in-place) -----------
__global__ __launch_bounds__(256) void fin_kernel(float* __restrict__ out,      // = num0
                                                  const float* __restrict__ nums,
                                                  const float* __restrict__ dens) {
    const int idx = blockIdx.x * 256 + threadIdx.x;
    const int i = idx >> 7;                         // FOUT = 128
    const size_t NF = (size_t)N_NODES * FOUT;
    float numv = out[idx];
#pragma unroll
    for (int k = 0; k < JS - 1; ++k) numv += nums[k * NF + idx];
    float denv = 0.f;
#pragma unroll
    for (int k = 0; k < JS; ++k) denv += dens[k * N_NODES + i];
    float v = numv / fmaxf(denv, 1e-30f);
    out[idx] = (v > 0.f) ? v : expm1f(v);
}

extern "C" void kernel_launch(void* const* d_in, const int* in_sizes, int n_in,
                              void* d_out, int out_size, void* d_ws, size_t ws_size,
                              hipStream_t stream) {
    const float* h   = (const float*)d_in[0];
    const int*   adj = (const int*)d_in[1];
    const float* W   = (const float*)d_in[2];
    const float* a1  = (const float*)d_in[3];
    const float* a2  = (const float*)d_in[4];

    // d_ws layout (~33 MB used):
    //   [0, 2MB)   whB (bf16, fragment-ordered)
    //   [2MB..)    s1 | s2 | dens(8xN) | nums(7 x N*FOUT)
    char* ws = (char*)d_ws;
    unsigned short* whB = (unsigned short*)ws;
    float* s1   = (float*)(ws + (2u << 20));
    float* s2   = s1 + N_NODES;
    float* dens = s2 + N_NODES;
    float* nums = dens + JS * N_NODES;
    float* out  = (float*)d_out;

    wh_kernel<<<dim3(N_NODES / 64, FOUT / 32), 256, 0, stream>>>(h, W, whB);
    s_kernel<<<dim3(N_NODES / 64), 256, 0, stream>>>(whB, a1, a2, s1, s2);
    gat_kernel<<<dim3((N_NODES / 128) * JS), 256, 0, stream>>>(adj, whB, s1, s2,
                                                               out, nums, dens);
    fin_kernel<<<dim3(N_NODES * FOUT / 256), 256, 0, stream>>>(out, nums, dens);
}

// Round 11
// 443.151 us; speedup vs baseline: 1.0337x; 1.0067x over previous
//
#include <hip/hip_runtime.h>
#include <cstdint>
#include <cstddef>

// Dtypes PROVEN fp32 (R2 bf16-read -> NaN; R4 fp32-read -> pass, absmax 0.0078).
#define N_NODES 8192
#define FIN 256
#define FOUT 128
#define JS 16                 // j slices (partial softmax, merged in fin_kernel)
#define JW (N_NODES / JS)     // 512 columns per slice
#define KCH (JW / 32)         // 16 k-chunks of 32 cols per wave
#define LOG2E 1.4426950408889634f

typedef __attribute__((ext_vector_type(8))) short bf16x8;
typedef __attribute__((ext_vector_type(4))) float f32x4;
typedef __attribute__((ext_vector_type(4))) int i32x4;

__device__ __forceinline__ float bf2f(unsigned short u) {
    union { unsigned int i; float f; } v; v.i = ((unsigned int)u) << 16; return v.f;
}
__device__ __forceinline__ unsigned short f2bf(float f) {
    union { float f; unsigned int i; } v; v.f = f;
    unsigned int r = (v.i + 0x7FFFu + ((v.i >> 16) & 1u)) >> 16;
    return (unsigned short)r;
}
__device__ __forceinline__ unsigned int pack_bf16(float a, float b) {
    return (unsigned)f2bf(a) | ((unsigned)f2bf(b) << 16);
}

// whB fragment-order layout: tile (kb, fb) holds Wh[j=kb*32+quad*8+e][f=fb*16+sl]
// at element ((kb*8+fb)*512 + (quad*16+sl)*8 + e) -> a wave's B-load is one
// contiguous 1 KB burst.
__device__ __forceinline__ size_t whb_idx(int j, int f) {
    return ((size_t)((j >> 5) * 8 + (f >> 4)) << 9) + (((j >> 3) & 3) << 7)
         + ((f & 15) << 3) + (j & 7);
}

// ---------------- Kernel A: whB = fragment-ordered bf16 (h @ W^T) -------------
__global__ __launch_bounds__(256) void wh_kernel(const float* __restrict__ h,
                                                 const float* __restrict__ W,
                                                 unsigned short* __restrict__ whB) {
    __shared__ float hT[64][FIN + 5];   // stride 261 (odd)
    const int t = threadIdx.x;
    const int i0 = blockIdx.x * 64;
    const int f0 = blockIdx.y * 32;
#pragma unroll
    for (int c = 0; c < 16; ++c) {       // 64x256 floats, float4-coalesced
        int chunk = c * 256 + t;
        int row = chunk >> 6, col = (chunk & 63) * 4;
        f32x4 v = *(const f32x4*)&h[(size_t)(i0 + row) * FIN + col];
        hT[row][col] = v[0]; hT[row][col + 1] = v[1];
        hT[row][col + 2] = v[2]; hT[row][col + 3] = v[3];
    }
    __syncthreads();
    const int lane = t & 63;
    const int fb8 = __builtin_amdgcn_readfirstlane(f0 + (t >> 6) * 8); // wave -> 8 f
    const float* w0 = W + (size_t)fb8 * FIN;
    float acc[8] = {0.f, 0.f, 0.f, 0.f, 0.f, 0.f, 0.f, 0.f};
    for (int k = 0; k < FIN; k += 4) {
        float h0 = hT[lane][k],     h1 = hT[lane][k + 1];
        float h2 = hT[lane][k + 2], h3 = hT[lane][k + 3];
#pragma unroll
        for (int c = 0; c < 8; ++c) {
            const float* wr = w0 + c * FIN;   // uniform -> s_load
            acc[c] += h0 * wr[k] + h1 * wr[k + 1] + h2 * wr[k + 2] + h3 * wr[k + 3];
        }
    }
    const int i = i0 + lane;
#pragma unroll
    for (int c = 0; c < 8; ++c)
        whB[whb_idx(i, fb8 + c)] = f2bf(acc[c]);
}

// ---------------- Kernel B: s1'[i], s2'[i] = (Wh@a)*log2e --------------------
__global__ __launch_bounds__(256) void s_kernel(const unsigned short* __restrict__ whB,
                                                const float* __restrict__ a1,
                                                const float* __restrict__ a2,
                                                float* __restrict__ s1,
                                                float* __restrict__ s2) {
    __shared__ float p1[4][64], p2[4][64];
    const int t = threadIdx.x;
    const int l = t & 63;
    const int g = t >> 6;
    const int i = blockIdx.x * 64 + l;
    float acc1 = 0.f, acc2 = 0.f;
#pragma unroll
    for (int fb = g * 2; fb < g * 2 + 2; ++fb) {
#pragma unroll
        for (int sl = 0; sl < 16; ++sl) {
            int f = fb * 16 + sl;
            float v = bf2f(whB[whb_idx(i, f)]);
            acc1 += v * a1[f];
            acc2 += v * a2[f];
        }
    }
    p1[g][l] = acc1; p2[g][l] = acc2;
    __syncthreads();
    if (g == 0) {
        s1[i] = (p1[0][l] + p1[1][l] + p1[2][l] + p1[3][l]) * LOG2E;
        s2[i] = (p2[0][l] + p2[1][l] + p2[2][l] + p2[3][l]) * LOG2E;
    }
}

// ---------------- Kernel C: BARRIER-FREE fused mask+softmax+PV MFMA ----------
// Each wave owns 32 rows x JW cols in registers (no LDS, no __syncthreads).
// Grid 1024 blocks x 4 waves -> 4 blocks/CU, target 16 waves/CU resident.
// B-fragments loaded in two 4-wide groups to keep VGPR+AGPR under the
// 128/wave threshold (4 waves/SIMD).
__global__ __launch_bounds__(256) void gat_kernel(const int* __restrict__ adj,
                                                  const unsigned short* __restrict__ whB,
                                                  const float* __restrict__ s1,
                                                  const float* __restrict__ s2,
                                                  float* __restrict__ out,     // slice-0 num
                                                  float* __restrict__ nums,    // slices 1..15
                                                  float* __restrict__ dens) {  // 16 x N
    const int t = threadIdx.x;
    const int w = t >> 6;
    const int lane = t & 63;
    const int sl = lane & 15;
    const int quad = lane >> 4;
    const int slice = blockIdx.x & (JS - 1);
    const int rg = (blockIdx.x >> 4) * 4 + w;        // 0..255 row-group
    const int row0 = rg * 32;
    const int jb = slice * JW;
    float* __restrict__ num = slice ? (nums + (size_t)(slice - 1) * N_NODES * FOUT) : out;
    float* __restrict__ den = dens + (size_t)slice * N_NODES;

    const float s1a = s1[row0 + sl];                 // row of m-tile 0
    const float s1b = s1[row0 + 16 + sl];            // row of m-tile 1
    const int* aR0 = adj + (size_t)(row0 + sl) * N_NODES + jb + quad * 8;
    const int* aR1 = aR0 + (size_t)16 * N_NODES;
    const float* s2p = s2 + jb + quad * 8;

    f32x4 acc[2][8];
#pragma unroll
    for (int m = 0; m < 2; ++m)
#pragma unroll
        for (int fb = 0; fb < 8; ++fb) acc[m][fb] = (f32x4){0.f, 0.f, 0.f, 0.f};

    float d0 = 0.f, d1 = 0.f;

    // register prefetch, depth 1 (no barriers -> loads fly across iterations)
    i32x4 pa0 = *(const i32x4*)(aR0);
    i32x4 pa1 = *(const i32x4*)(aR0 + 4);
    i32x4 pb0 = *(const i32x4*)(aR1);
    i32x4 pb1 = *(const i32x4*)(aR1 + 4);
    f32x4 ps0 = *(const f32x4*)(s2p);
    f32x4 ps1 = *(const f32x4*)(s2p + 4);

#pragma unroll 1
    for (int ch = 0; ch < KCH; ++ch) {
        i32x4 ca0 = pa0, ca1 = pa1, cb0 = pb0, cb1 = pb1;
        f32x4 cs0 = ps0, cs1 = ps1;
        if (ch + 1 < KCH) {
            int o = (ch + 1) * 32;
            pa0 = *(const i32x4*)(aR0 + o);
            pa1 = *(const i32x4*)(aR0 + o + 4);
            pb0 = *(const i32x4*)(aR1 + o);
            pb1 = *(const i32x4*)(aR1 + o + 4);
            ps0 = *(const f32x4*)(s2p + o);
            ps1 = *(const f32x4*)(s2p + o + 4);
        }
        const int kb = jb / 32 + ch;
        const unsigned short* bp = whB + ((size_t)(kb * 8) << 9) + lane * 8;
        // ---- B group 0 issued before P-build (latency overlaps VALU) ----
        bf16x8 Ba[4];
#pragma unroll
        for (int fb = 0; fb < 4; ++fb) Ba[fb] = *(const bf16x8*)(bp + ((size_t)fb << 9));
        // ---- P in A-frag layout: lane holds P[sl][quad*8+e], e=0..7 ----
        float p0[8], p1[8];
#pragma unroll
        for (int e = 0; e < 8; ++e) {
            float sc = (e < 4) ? cs0[e] : cs1[e - 4];
            int m0 = (e < 4) ? ca0[e] : ca1[e - 4];
            int m1 = (e < 4) ? cb0[e] : cb1[e - 4];
            float y0 = s1a + sc;
            float y1 = s1b + sc;
            y0 = fmaxf(y0, 0.2f * y0);               // leaky (exp2 domain)
            y1 = fmaxf(y1, 0.2f * y1);
            float e0 = __builtin_amdgcn_exp2f(y0);
            float e1 = __builtin_amdgcn_exp2f(y1);
            p0[e] = (m0 > 0) ? e0 : 0.f;
            p1[e] = (m1 > 0) ? e1 : 0.f;
            d0 += p0[e];
            d1 += p1[e];
        }
        union { bf16x8 v; unsigned int u[4]; } A0, A1;
#pragma unroll
        for (int q = 0; q < 4; ++q) {
            A0.u[q] = pack_bf16(p0[2 * q], p0[2 * q + 1]);
            A1.u[q] = pack_bf16(p1[2 * q], p1[2 * q + 1]);
        }
        // ---- MFMA group 0 ----
#pragma unroll
        for (int fb = 0; fb < 4; ++fb) {
            acc[0][fb] = __builtin_amdgcn_mfma_f32_16x16x32_bf16(A0.v, Ba[fb], acc[0][fb], 0, 0, 0);
            acc[1][fb] = __builtin_amdgcn_mfma_f32_16x16x32_bf16(A1.v, Ba[fb], acc[1][fb], 0, 0, 0);
        }
        // ---- B group 1 + MFMA group 1 (latency covered by co-resident waves) ----
        bf16x8 Bb[4];
#pragma unroll
        for (int fb = 0; fb < 4; ++fb) Bb[fb] = *(const bf16x8*)(bp + ((size_t)(4 + fb) << 9));
#pragma unroll
        for (int fb = 0; fb < 4; ++fb) {
            acc[0][4 + fb] = __builtin_amdgcn_mfma_f32_16x16x32_bf16(A0.v, Bb[fb], acc[0][4 + fb], 0, 0, 0);
            acc[1][4 + fb] = __builtin_amdgcn_mfma_f32_16x16x32_bf16(A1.v, Bb[fb], acc[1][4 + fb], 0, 0, 0);
        }
    }
    // ---- denominator: reduce across quads (lanes sl, sl+16, sl+32, sl+48) ----
    d0 += __shfl_xor(d0, 16); d0 += __shfl_xor(d0, 32);
    d1 += __shfl_xor(d1, 16); d1 += __shfl_xor(d1, 32);
    if (lane < 16) {
        den[row0 + lane] = d0;
        den[row0 + 16 + lane] = d1;
    }
    // ---- epilogue: raw partials (divide + ELU in fin_kernel) ----
#pragma unroll
    for (int m = 0; m < 2; ++m)
#pragma unroll
        for (int fb = 0; fb < 8; ++fb)
#pragma unroll
            for (int r = 0; r < 4; ++r) {
                int row = row0 + m * 16 + quad * 4 + r;   // D: row=quad*4+r, col=sl
                num[(size_t)row * FOUT + fb * 16 + sl] = acc[m][fb][r];
            }
}

// ---------------- Kernel D: merge 16 slices, divide, ELU (in-place) ----------
__global__ __launch_bounds__(256) void fin_kernel(float* __restrict__ out,      // = num0
                                                  const float* __restrict__ nums,
                                                  const float* __restrict__ dens) {
    const int idx = blockIdx.x * 256 + threadIdx.x;
    const int i = idx >> 7;                         // FOUT = 128
    const size_t NF = (size_t)N_NODES * FOUT;
    float numv = out[idx];
#pragma unroll
    for (int k = 0; k < JS - 1; ++k) numv += nums[k * NF + idx];
    float denv = 0.f;
#pragma unroll
    for (int k = 0; k < JS; ++k) denv += dens[k * N_NODES + i];
    float v = numv / fmaxf(denv, 1e-30f);
    out[idx] = (v > 0.f) ? v : expm1f(v);
}

extern "C" void kernel_launch(void* const* d_in, const int* in_sizes, int n_in,
                              void* d_out, int out_size, void* d_ws, size_t ws_size,
                              hipStream_t stream) {
    const float* h   = (const float*)d_in[0];
    const int*   adj = (const int*)d_in[1];
    const float* W   = (const float*)d_in[2];
    const float* a1  = (const float*)d_in[3];
    const float* a2  = (const float*)d_in[4];

    // d_ws layout (~63 MB used):
    //   [0, 2MB)   whB (bf16, fragment-ordered)
    //   [2MB..)    s1 | s2 | dens(16xN) | nums(15 x N*FOUT)
    char* ws = (char*)d_ws;
    unsigned short* whB = (unsigned short*)ws;
    float* s1   = (float*)(ws + (2u << 20));
    float* s2   = s1 + N_NODES;
    float* dens = s2 + N_NODES;
    float* nums = dens + JS * N_NODES;
    float* out  = (float*)d_out;

    wh_kernel<<<dim3(N_NODES / 64, FOUT / 32), 256, 0, stream>>>(h, W, whB);
    s_kernel<<<dim3(N_NODES / 64), 256, 0, stream>>>(whB, a1, a2, s1, s2);
    gat_kernel<<<dim3((N_NODES / 128) * JS), 256, 0, stream>>>(adj, whB, s1, s2,
                                                               out, nums, dens);
    fin_kernel<<<dim3(N_NODES * FOUT / 256), 256, 0, stream>>>(out, nums, dens);
}